// Round 1
// baseline (423.473 us; speedup 1.0000x reference)
//
#include <hip/hip_runtime.h>

#define NR 65536
#define DIN 512
#define H 10
#define G4 40
#define EPSB 1e-5f
#define CHUNK 64
#define WARM 128
#define NCHUNK (NR / CHUNK)   // 1024

__device__ __forceinline__ float fast_sigmoid(float x) {
  return 1.0f / (1.0f + __expf(-x));
}
__device__ __forceinline__ float fast_tanh(float x) {
  // 1 - 2/(exp(2x)+1); saturates correctly at +-inf
  return 1.0f - 2.0f / (__expf(2.0f * x) + 1.0f);
}
__device__ __forceinline__ float rlane(float v, int l) {
  return __int_as_float(__builtin_amdgcn_readlane(__float_as_int(v), l));
}

// ---------------- K0: zero the atomic-accumulated stats (ws is 0xAA-poisoned)
__global__ void k0_zero(float* __restrict__ s) {
  if (threadIdx.x < 64) s[threadIdx.x] = 0.0f;
}

// ---------------- K1: y = x @ W1^T + b1, accumulate col sums / sumsq for BN1
__global__ __launch_bounds__(256) void k1_proj(const float* __restrict__ x,
                                               const float* __restrict__ W1,
                                               const float* __restrict__ b1,
                                               float* __restrict__ y,
                                               float* __restrict__ stats1) {
  __shared__ float w1s[H * DIN];     // 20 KB
  __shared__ float red[256 * 20];    // 20 KB
  const int tid = threadIdx.x;
  for (int i = tid; i < H * DIN; i += 256) w1s[i] = W1[i];
  __syncthreads();

  const int t = blockIdx.x * 256 + tid;
  float acc[H];
#pragma unroll
  for (int j = 0; j < H; ++j) acc[j] = b1[j];

  const float4* xr = (const float4*)(x + (size_t)t * DIN);
#pragma unroll 2
  for (int d4 = 0; d4 < DIN / 4; ++d4) {
    float4 xv = xr[d4];
#pragma unroll
    for (int j = 0; j < H; ++j) {
      float4 wv = *(const float4*)&w1s[j * DIN + d4 * 4];
      acc[j] = fmaf(xv.x, wv.x, acc[j]);
      acc[j] = fmaf(xv.y, wv.y, acc[j]);
      acc[j] = fmaf(xv.z, wv.z, acc[j]);
      acc[j] = fmaf(xv.w, wv.w, acc[j]);
    }
  }
#pragma unroll
  for (int j = 0; j < H; ++j) {
    y[(size_t)t * H + j] = acc[j];
    red[tid * 20 + j] = acc[j];
    red[tid * 20 + 10 + j] = acc[j] * acc[j];
  }
  __syncthreads();
  if (tid < 20) {
    float s = 0.0f;
    for (int i = 0; i < 256; ++i) s += red[i * 20 + tid];
    atomicAdd(&stats1[tid], s);
  }
}

// ---------------- K2: xg[t][k*4+g] = sum_m W_ih[g*10+k][m] * bn1(y[t][m])
__global__ __launch_bounds__(256) void k2_xg(const float* __restrict__ y,
                                             const float* __restrict__ stats1,
                                             const float* __restrict__ g1,
                                             const float* __restrict__ be1,
                                             const float* __restrict__ Wih,
                                             float* __restrict__ xg) {
  __shared__ float wl[G4 * H];
  __shared__ float A[H], B[H];
  const int tid = threadIdx.x;
  for (int i = tid; i < G4 * H; i += 256) wl[i] = Wih[i];
  if (tid < H) {
    float m = stats1[tid] * (1.0f / NR);
    float v = stats1[10 + tid] * (1.0f / NR) - m * m;
    float inv = rsqrtf(v + EPSB);
    A[tid] = inv * g1[tid];
    B[tid] = be1[tid] - m * inv * g1[tid];
  }
  __syncthreads();

  const int t = blockIdx.x * 256 + tid;
  float x1[H];
#pragma unroll
  for (int m = 0; m < H; ++m) x1[m] = fmaf(y[(size_t)t * H + m], A[m], B[m]);

  float out[G4];
#pragma unroll
  for (int g = 0; g < 4; ++g) {
#pragma unroll
    for (int k = 0; k < H; ++k) {
      const int j = g * H + k;
      float s = 0.0f;
#pragma unroll
      for (int m = 0; m < H; ++m) s = fmaf(wl[j * H + m], x1[m], s);
      out[k * 4 + g] = s;
    }
  }
  float4* o4 = (float4*)(xg + (size_t)t * G4);
#pragma unroll
  for (int q = 0; q < G4 / 4; ++q) o4[q] = ((const float4*)out)[q];
}

// ---------------- K3: the chunked warm-up scan. 1 block = 1 wave = 1 chunk.
__device__ __forceinline__ void lstm_cell(float hin, float cin, float add0,
                                          float add1, float add2, float add3,
                                          const float (&whh)[4][H],
                                          const float (&bias)[4], float& hout,
                                          float& cout) {
  float a0 = bias[0] + add0, a1 = bias[1] + add1;
  float a2 = bias[2] + add2, a3 = bias[3] + add3;
#pragma unroll
  for (int m = 0; m < H; ++m) {
    float hm = rlane(hin, m);
    a0 = fmaf(whh[0][m], hm, a0);
    a1 = fmaf(whh[1][m], hm, a1);
    a2 = fmaf(whh[2][m], hm, a2);
    a3 = fmaf(whh[3][m], hm, a3);
  }
  float ig = fast_sigmoid(a0);
  float fg = fast_sigmoid(a1);
  float gg = fast_tanh(a2);
  float og = fast_sigmoid(a3);
  cout = fmaf(fg, cin, ig * gg);
  hout = og * fast_tanh(cout);
}

__global__ __launch_bounds__(64) void k3_scan(const float* __restrict__ xg,
                                              const int* __restrict__ zp_arr,
                                              const int* __restrict__ broad,
                                              const float* __restrict__ Whh,
                                              const float* __restrict__ bih,
                                              const float* __restrict__ bhh,
                                              float* __restrict__ outs,
                                              float* __restrict__ stats2) {
  const int k = threadIdx.x;
  if (k >= H) return;  // lanes 0..9 own hidden units
  const int cid = blockIdx.x;

  float whh[4][H];
  float bias[4];
#pragma unroll
  for (int g = 0; g < 4; ++g) {
    const int j = g * H + k;
    bias[g] = bih[j] + bhh[j];
#pragma unroll
    for (int m = 0; m < H; ++m) whh[g][m] = Whh[j * H + m];
  }

  const int t_out0 = cid * CHUNK;
  const int t_end = t_out0 + CHUNK;
  int t0 = t_out0 - WARM;
  if (t0 < 0) t0 = 0;
  // snap warm-up start back to a group start (running sums exactly zero there)
  while (t0 > 0 && broad[t0] == broad[t0 - 1]) --t0;

  float hs = 0.0f, cs = 0.0f;       // state (guess = 0; decays over warm-up)
  float sh = 0.0f, sc = 0.0f, cnt = 0.0f;
  float s1 = 0.0f, s2 = 0.0f;       // bn2 partial stats for unit k
  int bid_cur = broad[t0];

  for (int t = t0; t < t_end; ++t) {
    // per-step scalars + leaf input (issued early so pads hide the latency)
    const float4 xv = *(const float4*)(xg + (size_t)t * G4 + k * 4);
    const int zp = zp_arr[t];
    const int bid_next = (t + 1 < NR) ? broad[t + 1] : -1;
    const bool bnd = (t == NR - 1) || (bid_next != bid_cur);

    for (int p = 0; p < zp; ++p)  // zero-input pad cells (update state)
      lstm_cell(hs, cs, 0.0f, 0.0f, 0.0f, 0.0f, whh, bias, hs, cs);

    // leaf cell (does NOT update state)
    float ht, ct;
    lstm_cell(hs, cs, xv.x, xv.y, xv.z, xv.w, whh, bias, ht, ct);
    sh += ht;
    sc += ct;
    cnt += 1.0f;

    if (t >= t_out0) {
      outs[(size_t)t * H + k] = ht;
      s1 += ht;
      s2 += ht * ht;
    }
    if (bnd) {
      hs = sh / cnt;
      cs = sc / cnt;
      sh = 0.0f;
      sc = 0.0f;
      cnt = 0.0f;
    }
    bid_cur = bid_next;
  }
  atomicAdd(&stats2[k], s1);
  atomicAdd(&stats2[10 + k], s2);
}

// ---------------- K5: out = tanh(bn2(outs) @ W2^T + b2), BN folded to a,b
__global__ __launch_bounds__(256) void k5_out(const float* __restrict__ outs,
                                              const float* __restrict__ stats2,
                                              const float* __restrict__ g2,
                                              const float* __restrict__ be2,
                                              const float* __restrict__ W2,
                                              const float* __restrict__ b2,
                                              float* __restrict__ out) {
  __shared__ float a2s[H];
  __shared__ float b2s;
  const int tid = threadIdx.x;
  if (tid == 0) {
    float bacc = b2[0];
    for (int j = 0; j < H; ++j) {
      float m = stats2[j] * (1.0f / NR);
      float v = stats2[10 + j] * (1.0f / NR) - m * m;
      float inv = rsqrtf(v + EPSB);
      a2s[j] = inv * g2[j] * W2[j];
      bacc += (be2[j] - m * inv * g2[j]) * W2[j];
    }
    b2s = bacc;
  }
  __syncthreads();
  const int t = blockIdx.x * 256 + tid;
  float s = b2s;
  const float* r = outs + (size_t)t * H;
#pragma unroll
  for (int j = 0; j < H; ++j) s = fmaf(r[j], a2s[j], s);
  out[t] = fast_tanh(s);
}

extern "C" void kernel_launch(void* const* d_in, const int* in_sizes, int n_in,
                              void* d_out, int out_size, void* d_ws,
                              size_t ws_size, hipStream_t stream) {
  const float* x = (const float*)d_in[0];
  const int* zp = (const int*)d_in[1];
  const int* broad = (const int*)d_in[2];
  const float* W1 = (const float*)d_in[3];
  const float* b1 = (const float*)d_in[4];
  const float* g1 = (const float*)d_in[5];
  const float* be1 = (const float*)d_in[6];
  const float* Wih = (const float*)d_in[7];
  const float* Whh = (const float*)d_in[8];
  const float* bih = (const float*)d_in[9];
  const float* bhh = (const float*)d_in[10];
  const float* g2 = (const float*)d_in[11];
  const float* be2 = (const float*)d_in[12];
  const float* W2 = (const float*)d_in[13];
  const float* b2 = (const float*)d_in[14];
  float* out = (float*)d_out;

  float* ws = (float*)d_ws;
  float* stats1 = ws;                      // 32 floats reserved
  float* stats2 = ws + 32;                 // 32 floats reserved
  float* y = ws + 64;                      // N*10
  float* xg = y + (size_t)NR * H;          // N*40
  float* outs = y;                         // reuse y region (dead after K2)
  // total ws use: (64 + N*10 + N*40)*4 B = ~13.1 MB

  k0_zero<<<dim3(1), dim3(64), 0, stream>>>(ws);
  k1_proj<<<dim3(NR / 256), dim3(256), 0, stream>>>(x, W1, b1, y, stats1);
  k2_xg<<<dim3(NR / 256), dim3(256), 0, stream>>>(y, stats1, g1, be1, Wih, xg);
  k3_scan<<<dim3(NCHUNK), dim3(64), 0, stream>>>(xg, zp, broad, Whh, bih, bhh,
                                                 outs, stats2);
  k5_out<<<dim3(NR / 256), dim3(256), 0, stream>>>(outs, stats2, g2, be2, W2,
                                                   b2, out);
  (void)in_sizes; (void)n_in; (void)out_size; (void)ws_size;
}

// Round 2
// 370.129 us; speedup vs baseline: 1.1441x; 1.1441x over previous
//
#include <hip/hip_runtime.h>

#define NR 65536
#define DIN 512
#define H 10
#define G4 40
#define EPSB 1e-5f
#define CHUNK 64
#define WARM 128
#define NCHUNK (NR / CHUNK)   // 1024
#define SMAX (WARM + CHUNK)   // 192 staged steps max

__device__ __forceinline__ float fast_rcp(float x) {
  return __builtin_amdgcn_rcpf(x);
}
__device__ __forceinline__ float fast_sigmoid(float x) {
  return fast_rcp(1.0f + __expf(-x));
}
__device__ __forceinline__ float fast_tanh(float x) {
  return 1.0f - 2.0f * fast_rcp(__expf(2.0f * x) + 1.0f);
}
__device__ __forceinline__ float rlane(float v, int l) {
  return __int_as_float(__builtin_amdgcn_readlane(__float_as_int(v), l));
}

// ---------------- K0: zero the atomic-accumulated stats (ws is 0xAA-poisoned)
__global__ void k0_zero(float* __restrict__ s) {
  if (threadIdx.x < 64) s[threadIdx.x] = 0.0f;
}

// ---------------- K1: y = x @ W1^T + b1  (wave-per-row, W in registers)
// grid 512 x 256; wave gw handles rows r = gw + i*2048, i<32
__global__ __launch_bounds__(256) void k1_proj(const float* __restrict__ x,
                                               const float* __restrict__ W1,
                                               const float* __restrict__ b1,
                                               float* __restrict__ y,
                                               float* __restrict__ stats1) {
  const int tid = threadIdx.x;
  const int lane = tid & 63;
  const int wv = tid >> 6;
  const int gw = blockIdx.x * 4 + wv;  // 0..2047

  float w[H][8];
#pragma unroll
  for (int j = 0; j < H; ++j) {
    float4 a = *(const float4*)&W1[j * DIN + lane * 8];
    float4 b = *(const float4*)&W1[j * DIN + lane * 8 + 4];
    w[j][0] = a.x; w[j][1] = a.y; w[j][2] = a.z; w[j][3] = a.w;
    w[j][4] = b.x; w[j][5] = b.y; w[j][6] = b.z; w[j][7] = b.w;
  }
  const float bj = (lane < H) ? b1[lane] : 0.0f;
  float s1 = 0.0f, s2 = 0.0f;

  float4 xa = *(const float4*)&x[(size_t)gw * DIN + lane * 8];
  float4 xb = *(const float4*)&x[(size_t)gw * DIN + lane * 8 + 4];

  for (int i = 0; i < 32; ++i) {
    const int r = gw + i * 2048;
    const int rn = (i + 1 < 32) ? r + 2048 : r;
    float4 na = *(const float4*)&x[(size_t)rn * DIN + lane * 8];
    float4 nb = *(const float4*)&x[(size_t)rn * DIN + lane * 8 + 4];

    float acc[H];
#pragma unroll
    for (int j = 0; j < H; ++j) {
      float s = xa.x * w[j][0];
      s = fmaf(xa.y, w[j][1], s);
      s = fmaf(xa.z, w[j][2], s);
      s = fmaf(xa.w, w[j][3], s);
      s = fmaf(xb.x, w[j][4], s);
      s = fmaf(xb.y, w[j][5], s);
      s = fmaf(xb.z, w[j][6], s);
      s = fmaf(xb.w, w[j][7], s);
      acc[j] = s;
    }
#pragma unroll
    for (int off = 1; off < 64; off <<= 1) {
#pragma unroll
      for (int j = 0; j < H; ++j) acc[j] += __shfl_xor(acc[j], off);
    }
    // lane j takes acc[j] without dynamic reg indexing
    float v = acc[0];
#pragma unroll
    for (int j = 1; j < H; ++j) v = (lane == j) ? acc[j] : v;
    if (lane < H) {
      v += bj;
      y[(size_t)r * H + lane] = v;
      s1 += v;
      s2 += v * v;
    }
    xa = na; xb = nb;
  }

  __shared__ float red[4][2 * H];
  if (lane < H) { red[wv][lane] = s1; red[wv][H + lane] = s2; }
  __syncthreads();
  if (tid < 2 * H) {
    float s = red[0][tid] + red[1][tid] + red[2][tid] + red[3][tid];
    atomicAdd(&stats1[tid], s);
  }
}

// ---------------- K2: xg[t][k*4+g] = sum_m W_ih[g*10+k][m] * bn1(y[t][m])
__global__ __launch_bounds__(256) void k2_xg(const float* __restrict__ y,
                                             const float* __restrict__ stats1,
                                             const float* __restrict__ g1,
                                             const float* __restrict__ be1,
                                             const float* __restrict__ Wih,
                                             float* __restrict__ xg) {
  __shared__ float wl[G4 * H];
  __shared__ float A[H], B[H];
  const int tid = threadIdx.x;
  for (int i = tid; i < G4 * H; i += 256) wl[i] = Wih[i];
  if (tid < H) {
    float m = stats1[tid] * (1.0f / NR);
    float v = stats1[H + tid] * (1.0f / NR) - m * m;
    float inv = rsqrtf(v + EPSB);
    A[tid] = inv * g1[tid];
    B[tid] = be1[tid] - m * inv * g1[tid];
  }
  __syncthreads();

  const int t = blockIdx.x * 256 + tid;
  float x1[H];
#pragma unroll
  for (int m = 0; m < H; ++m) x1[m] = fmaf(y[(size_t)t * H + m], A[m], B[m]);

  float out[G4];
#pragma unroll
  for (int g = 0; g < 4; ++g) {
#pragma unroll
    for (int k = 0; k < H; ++k) {
      const int j = g * H + k;
      float s = 0.0f;
#pragma unroll
      for (int m = 0; m < H; ++m) s = fmaf(wl[j * H + m], x1[m], s);
      out[k * 4 + g] = s;
    }
  }
  float4* o4 = (float4*)(xg + (size_t)t * G4);
#pragma unroll
  for (int q = 0; q < G4 / 4; ++q) o4[q] = ((const float4*)out)[q];
}

// ---------------- K3: chunked warm-up scan, inputs staged through LDS
__device__ __forceinline__ void lstm_cell(float hin, float cin, float add0,
                                          float add1, float add2, float add3,
                                          const float (&whh)[4][H],
                                          const float (&bias)[4], float& hout,
                                          float& cout) {
  float a0 = bias[0] + add0, a1 = bias[1] + add1;
  float a2 = bias[2] + add2, a3 = bias[3] + add3;
#pragma unroll
  for (int m = 0; m < H; ++m) {
    float hm = rlane(hin, m);
    a0 = fmaf(whh[0][m], hm, a0);
    a1 = fmaf(whh[1][m], hm, a1);
    a2 = fmaf(whh[2][m], hm, a2);
    a3 = fmaf(whh[3][m], hm, a3);
  }
  float ig = fast_sigmoid(a0);
  float fg = fast_sigmoid(a1);
  float gg = fast_tanh(a2);
  float og = fast_sigmoid(a3);
  cout = fmaf(fg, cin, ig * gg);
  hout = og * fast_tanh(cout);
}

__global__ __launch_bounds__(64) void k3_scan(const float* __restrict__ xg,
                                              const int* __restrict__ zp_arr,
                                              const int* __restrict__ broad,
                                              const float* __restrict__ Whh,
                                              const float* __restrict__ bih,
                                              const float* __restrict__ bhh,
                                              float* __restrict__ outs,
                                              float* __restrict__ stats2) {
  __shared__ __align__(16) float sxg[SMAX * G4];  // 30720 B
  __shared__ int szp[SMAX];
  __shared__ int sbr[SMAX + 1];

  const int lane = threadIdx.x;
  const int cid = blockIdx.x;
  const int t_out0 = cid * CHUNK;
  const int t_end = t_out0 + CHUNK;
  int t0 = t_out0 - WARM;
  if (t0 < 0) t0 = 0;
  const int S = t_end - t0;

  // ---- cooperative staging (all 64 lanes), coalesced
  {
    const float4* src = (const float4*)(xg + (size_t)t0 * G4);
    float4* dst = (float4*)sxg;
    for (int i = lane; i < S * (G4 / 4); i += 64) dst[i] = src[i];
    for (int i = lane; i < S; i += 64) szp[i] = zp_arr[t0 + i];
    for (int i = lane; i <= S; i += 64) {
      int t = t0 + i;
      sbr[i] = (t < NR) ? broad[t] : -1;
    }
  }
  __syncthreads();

  const int k = lane;
  if (k >= H) return;

  float whh[4][H];
  float bias[4];
#pragma unroll
  for (int g = 0; g < 4; ++g) {
    const int j = g * H + k;
    bias[g] = bih[j] + bhh[j];
#pragma unroll
    for (int m = 0; m < H; ++m) whh[g][m] = Whh[j * H + m];
  }

  float hs = 0.0f, cs = 0.0f;  // zero state guess; decays over warm-up
  float sh = 0.0f, sc = 0.0f, cnt = 0.0f;
  float s1 = 0.0f, s2 = 0.0f;

  int bid_cur = sbr[0];
  int bid_nxt = sbr[1];
  float4 xv = *(const float4*)&sxg[0 * G4 + k * 4];
  int zp = szp[0];

  for (int s = 0; s < S; ++s) {
    // prefetch step s+1 from LDS (clamped; garbage-free, discarded on last)
    const int sn = (s + 1 < S) ? s + 1 : S - 1;
    const int sb = (s + 2 <= S) ? s + 2 : S;
    float4 xv_n = *(const float4*)&sxg[sn * G4 + k * 4];
    int zp_n = szp[sn];
    int bid_n2 = sbr[sb];

    const bool bnd = (bid_nxt != bid_cur);

    for (int p = 0; p < zp; ++p)
      lstm_cell(hs, cs, 0.0f, 0.0f, 0.0f, 0.0f, whh, bias, hs, cs);

    float ht, ct;
    lstm_cell(hs, cs, xv.x, xv.y, xv.z, xv.w, whh, bias, ht, ct);
    sh += ht;
    sc += ct;
    cnt += 1.0f;

    if (t0 + s >= t_out0) {
      outs[(size_t)(t0 + s) * H + k] = ht;
      s1 += ht;
      s2 += ht * ht;
    }
    if (bnd) {
      float ricnt = fast_rcp(cnt);
      hs = sh * ricnt;
      cs = sc * ricnt;
      sh = 0.0f;
      sc = 0.0f;
      cnt = 0.0f;
    }
    bid_cur = bid_nxt;
    bid_nxt = bid_n2;
    xv = xv_n;
    zp = zp_n;
  }
  atomicAdd(&stats2[k], s1);
  atomicAdd(&stats2[H + k], s2);
}

// ---------------- K5: out = tanh(bn2(outs) @ W2^T + b2), BN folded to a,b
__global__ __launch_bounds__(256) void k5_out(const float* __restrict__ outs,
                                              const float* __restrict__ stats2,
                                              const float* __restrict__ g2,
                                              const float* __restrict__ be2,
                                              const float* __restrict__ W2,
                                              const float* __restrict__ b2,
                                              float* __restrict__ out) {
  __shared__ float a2s[H];
  __shared__ float b2s;
  const int tid = threadIdx.x;
  if (tid == 0) {
    float bacc = b2[0];
    for (int j = 0; j < H; ++j) {
      float m = stats2[j] * (1.0f / NR);
      float v = stats2[H + j] * (1.0f / NR) - m * m;
      float inv = rsqrtf(v + EPSB);
      a2s[j] = inv * g2[j] * W2[j];
      bacc += (be2[j] - m * inv * g2[j]) * W2[j];
    }
    b2s = bacc;
  }
  __syncthreads();
  const int t = blockIdx.x * 256 + tid;
  float s = b2s;
  const float* r = outs + (size_t)t * H;
#pragma unroll
  for (int j = 0; j < H; ++j) s = fmaf(r[j], a2s[j], s);
  out[t] = fast_tanh(s);
}

extern "C" void kernel_launch(void* const* d_in, const int* in_sizes, int n_in,
                              void* d_out, int out_size, void* d_ws,
                              size_t ws_size, hipStream_t stream) {
  const float* x = (const float*)d_in[0];
  const int* zp = (const int*)d_in[1];
  const int* broad = (const int*)d_in[2];
  const float* W1 = (const float*)d_in[3];
  const float* b1 = (const float*)d_in[4];
  const float* g1 = (const float*)d_in[5];
  const float* be1 = (const float*)d_in[6];
  const float* Wih = (const float*)d_in[7];
  const float* Whh = (const float*)d_in[8];
  const float* bih = (const float*)d_in[9];
  const float* bhh = (const float*)d_in[10];
  const float* g2 = (const float*)d_in[11];
  const float* be2 = (const float*)d_in[12];
  const float* W2 = (const float*)d_in[13];
  const float* b2 = (const float*)d_in[14];
  float* out = (float*)d_out;

  float* ws = (float*)d_ws;
  float* stats1 = ws;              // 32 floats
  float* stats2 = ws + 32;         // 32 floats
  float* y = ws + 64;              // N*10
  float* xg = y + (size_t)NR * H;  // N*40
  float* outs = y;                 // reuse y region (dead after K2)

  k0_zero<<<dim3(1), dim3(64), 0, stream>>>(ws);
  k1_proj<<<dim3(512), dim3(256), 0, stream>>>(x, W1, b1, y, stats1);
  k2_xg<<<dim3(NR / 256), dim3(256), 0, stream>>>(y, stats1, g1, be1, Wih, xg);
  k3_scan<<<dim3(NCHUNK), dim3(64), 0, stream>>>(xg, zp, broad, Whh, bih, bhh,
                                                 outs, stats2);
  k5_out<<<dim3(NR / 256), dim3(256), 0, stream>>>(outs, stats2, g2, be2, W2,
                                                   b2, out);
  (void)in_sizes; (void)n_in; (void)out_size; (void)ws_size;
}